// Round 14
// baseline (421.821 us; speedup 1.0000x reference)
//
#include <hip/hip_runtime.h>
#include <hip/hip_bf16.h>
#include <math.h>

typedef __bf16 bf16x8 __attribute__((ext_vector_type(8)));
typedef float  f32x4  __attribute__((ext_vector_type(4)));

#define MFMA16 __builtin_amdgcn_mfma_f32_16x16x32_bf16

__device__ __forceinline__ float silu_f(float v) {
    return v * __builtin_amdgcn_rcpf(1.0f + __expf(-v));
}

// LDS weight layout: Wt[j][k], bf16, 16B-chunk XOR swizzle:
// phys = j*K + (((k>>3) ^ (j&7))<<3) + (k&7)  -> ds_read_b128, 2-way max.

// ---- detector: is edge_index stored as int64 (odd words all zero)? ---------
__global__ void k_detect(const int* __restrict__ ei, int* __restrict__ flag) {
    __shared__ int red[256];
    int v = 0;
#pragma unroll
    for (int j = 0; j < 4; ++j) v |= ei[2 * (threadIdx.x * 4 + j) + 1];
    red[threadIdx.x] = v;
    __syncthreads();
    for (int s = 128; s > 0; s >>= 1) {
        if (threadIdx.x < s) red[threadIdx.x] |= red[threadIdx.x + s];
        __syncthreads();
    }
    if (threadIdx.x == 0) *flag = (red[0] == 0) ? 1 : 0;
}

// ---- CSR build --------------------------------------------------------------
__global__ __launch_bounds__(256) void k_hist(
    const int* __restrict__ ei, const int* __restrict__ flag,
    int* __restrict__ counts, int E)
{
    int e = blockIdx.x * 256 + threadIdx.x;
    if (e >= E) return;
    const int is64 = *flag;
    int r = is64 ? ei[2 * E + 2 * e] : ei[E + e];
    atomicAdd(&counts[r], 1);
}

__global__ __launch_bounds__(256) void k_scan1(
    const int* __restrict__ counts, int* __restrict__ offsets,
    int* __restrict__ partials, int N)
{
    __shared__ int pairv[256];
    __shared__ int buf[256];
    const int t = threadIdx.x;
    const int base = blockIdx.x * 512;
    int a = (base + 2 * t     < N) ? counts[base + 2 * t]     : 0;
    int b = (base + 2 * t + 1 < N) ? counts[base + 2 * t + 1] : 0;
    pairv[t] = a + b;
    buf[t]   = a + b;
    __syncthreads();
    for (int d = 1; d < 256; d <<= 1) {
        int v = buf[t];
        int w = (t >= d) ? buf[t - d] : 0;
        __syncthreads();
        buf[t] = v + w;
        __syncthreads();
    }
    int excl = buf[t] - pairv[t];
    if (base + 2 * t     < N) offsets[base + 2 * t]     = excl;
    if (base + 2 * t + 1 < N) offsets[base + 2 * t + 1] = excl + a;
    if (t == 255) partials[blockIdx.x] = buf[255];
}

__global__ void k_scan2(int* __restrict__ partials, int nblk) {
    __shared__ int buf[256];
    const int t = threadIdx.x;
    int v0 = (t < nblk) ? partials[t] : 0;
    buf[t] = v0;
    __syncthreads();
    for (int d = 1; d < 256; d <<= 1) {
        int v = buf[t];
        int w = (t >= d) ? buf[t - d] : 0;
        __syncthreads();
        buf[t] = v + w;
        __syncthreads();
    }
    if (t < nblk) partials[t] = buf[t] - v0;   // exclusive
}

__global__ __launch_bounds__(256) void k_scan3(
    int* __restrict__ offsets, const int* __restrict__ partials,
    int* __restrict__ cursor, int N)
{
    int i = blockIdx.x * 256 + threadIdx.x;
    if (i >= N) return;
    int v = offsets[i] + partials[i >> 9];
    offsets[i] = v;
    cursor[i]  = v;
}

// scatter + per-edge distance precompute (kills pos-gather chains downstream)
__global__ __launch_bounds__(256) void k_scatter(
    const int* __restrict__ ei, const int* __restrict__ flag,
    const float* __restrict__ pos, int* __restrict__ cursor,
    int* __restrict__ csr_s, int* __restrict__ csr_r,
    float* __restrict__ dist, int E)
{
    int e = blockIdx.x * 256 + threadIdx.x;
    if (e >= E) return;
    const int is64 = *flag;
    int s, r;
    if (is64) { s = ei[2 * e]; r = ei[2 * E + 2 * e]; }
    else      { s = ei[e];     r = ei[E + e];         }
    float dx = pos[3 * s]     - pos[3 * r];
    float dy = pos[3 * s + 1] - pos[3 * r + 1];
    float dz = pos[3 * s + 2] - pos[3 * r + 2];
    float d  = sqrtf(dx * dx + dy * dy + dz * dz);
    int slot = atomicAdd(&cursor[r], 1);
    csr_s[slot] = s;
    csr_r[slot] = r;
    dist[slot]  = d;
}

// ---- phase 1: AB[n][0:128]=bf16(x@W1a + b1), AB[n][128:256]=bf16(x@W1b) ----
__global__ __launch_bounds__(256) void k_node1(
    const float* __restrict__ x, const float* __restrict__ W1,
    const float* __restrict__ b1, __bf16* __restrict__ AB, int N, int ngroups)
{
    __shared__ __bf16 wt[256 * 128];
    for (int idx = threadIdx.x; idx < 256 * 128; idx += 256) {
        int j = idx & 255, k = idx >> 8;
        float w = (j < 128) ? W1[(k << 7) + j] : W1[((k + 128) << 7) + (j - 128)];
        wt[(j << 7) + ((((k >> 3) ^ (j & 7))) << 3) + (k & 7)] = (__bf16)w;
    }
    __syncthreads();

    const int lane = threadIdx.x & 63;
    const int row  = lane & 15;
    const int kq   = lane >> 4;

    for (int g = blockIdx.x; g < ngroups; g += gridDim.x) {
        const int row0 = g * 64 + (threadIdx.x >> 6) * 16;
        int m = row0 + row; if (m >= N) m = N - 1;
        const float* xr = x + (size_t)m * 128;

        bf16x8 afr[4];
#pragma unroll
        for (int c = 0; c < 4; ++c) {
            const int k0 = c * 32 + kq * 8;
            float4 a0 = *(const float4*)(xr + k0);
            float4 a1 = *(const float4*)(xr + k0 + 4);
            bf16x8 af;
            af[0]=(__bf16)a0.x; af[1]=(__bf16)a0.y; af[2]=(__bf16)a0.z; af[3]=(__bf16)a0.w;
            af[4]=(__bf16)a1.x; af[5]=(__bf16)a1.y; af[6]=(__bf16)a1.z; af[7]=(__bf16)a1.w;
            afr[c] = af;
        }

        f32x4 acc[16] = {};
#pragma unroll
        for (int t = 0; t < 16; ++t) {
            const int j  = t * 16 + row;
            const int jb = j & 7;
            const __bf16* base = wt + (j << 7);
#pragma unroll
            for (int c = 0; c < 4; ++c) {
                const int kb = c * 4 + kq;
                bf16x8 b = *(const bf16x8*)(base + ((kb ^ jb) << 3));
                acc[t] = MFMA16(afr[c], b, acc[t], 0, 0, 0);
            }
        }

#pragma unroll
        for (int t = 0; t < 16; ++t) {
            const int col = t * 16 + row;
            const float bb = (col < 128) ? b1[col] : 0.0f;
#pragma unroll
            for (int q = 0; q < 4; ++q) {
                const int gr = row0 + kq * 4 + q;
                if (gr < N) AB[(size_t)gr * 256 + col] = (__bf16)(acc[t][q] + bb);
            }
        }
    }
}

// ---- FUSED edge phase v3: wave-per-receiver, c-innermost, B in LDS ---------
// Register footprint by construction: ONE afr chunk live (4 VGPR), acc[8]=32,
// B-row in a per-wave LDS slot (not 16 VGPR), b2/w3 from LDS, dist precomp.
__global__ __launch_bounds__(256) void k_edge_f3(
    const __bf16* __restrict__ AB, const int* __restrict__ csr_s,
    const float* __restrict__ dist, const int* __restrict__ offs,
    const int* __restrict__ counts, const float* __restrict__ W2,
    const float* __restrict__ b2, const float* __restrict__ w3,
    float* __restrict__ aggr, int N)
{
    __shared__ __bf16 wt[128 * 128];     // 32 KB W2^T swizzled
    __shared__ float  w3s[128];
    __shared__ float  b2s[128];
    __shared__ __bf16 bsl[4][128];       // per-wave B-row slot (256 B each)
    for (int idx = threadIdx.x; idx < 128 * 128; idx += 256) {
        int j = idx & 127, k = idx >> 7;
        wt[(j << 7) + ((((k >> 3) ^ (j & 7))) << 3) + (k & 7)] = (__bf16)W2[(k << 7) + j];
    }
    for (int i = threadIdx.x; i < 128; i += 256) { w3s[i] = w3[i]; b2s[i] = b2[i]; }
    __syncthreads();

    const int lane = threadIdx.x & 63;
    const int row  = lane & 15;
    const int kq   = lane >> 4;
    const int wid  = threadIdx.x >> 6;
    const int wstep = gridDim.x * 4;

    for (int r = blockIdx.x * 4 + wid; r < N; r += wstep) {
        const int off = offs[r];
        const int deg = counts[r];

        // stage B[r] into this wave's LDS slot (wave-local, no barrier)
        if (lane < 16)
            *(bf16x8*)(&bsl[wid][lane * 8]) =
                *(const bf16x8*)(AB + (size_t)r * 256 + 128 + lane * 8);

        float colacc[8] = {0, 0, 0, 0, 0, 0, 0, 0};

        const int ntile = (deg + 15) >> 4;
        for (int tile = 0; tile < ntile; ++tile) {
            const int el  = tile * 16 + row;
            const int idx = off + ((el < deg) ? el : (deg - 1));
            const int s   = csr_s[idx];
            const float d = dist[idx];

            f32x4 acc[8] = {};
#pragma unroll
            for (int c = 0; c < 4; ++c) {
                const int k0 = c * 32 + kq * 8;
                bf16x8 a  = *(const bf16x8*)(AB + (size_t)s * 256 + k0);
                bf16x8 bb = *(const bf16x8*)(&bsl[wid][k0]);
                float4 w0 = *(const float4*)(w3s + k0);
                float4 w1 = *(const float4*)(w3s + k0 + 4);
                bf16x8 af;
                af[0] = (__bf16)silu_f((float)a[0] + (float)bb[0] + d * w0.x);
                af[1] = (__bf16)silu_f((float)a[1] + (float)bb[1] + d * w0.y);
                af[2] = (__bf16)silu_f((float)a[2] + (float)bb[2] + d * w0.z);
                af[3] = (__bf16)silu_f((float)a[3] + (float)bb[3] + d * w0.w);
                af[4] = (__bf16)silu_f((float)a[4] + (float)bb[4] + d * w1.x);
                af[5] = (__bf16)silu_f((float)a[5] + (float)bb[5] + d * w1.y);
                af[6] = (__bf16)silu_f((float)a[6] + (float)bb[6] + d * w1.z);
                af[7] = (__bf16)silu_f((float)a[7] + (float)bb[7] + d * w1.w);
                // feed this chunk to all 8 output tiles before next chunk:
                const int kb = c * 4 + kq;
#pragma unroll
                for (int t = 0; t < 8; ++t) {
                    const int j  = t * 16 + row;
                    const int jb = j & 7;
                    bf16x8 b = *(const bf16x8*)(wt + (j << 7) + ((kb ^ jb) << 3));
                    acc[t] = MFMA16(af, b, acc[t], 0, 0, 0);
                }
            }

#pragma unroll
            for (int t = 0; t < 8; ++t) {
                const float bb = b2s[t * 16 + row];
#pragma unroll
                for (int q = 0; q < 4; ++q) {
                    const int er = tile * 16 + kq * 4 + q;
                    if (er < deg) colacc[t] += silu_f(acc[t][q] + bb);
                }
            }
        }

#pragma unroll
        for (int t = 0; t < 8; ++t) {
            float v = colacc[t];
            v += __shfl_xor(v, 16, 64);
            v += __shfl_xor(v, 32, 64);
            colacc[t] = v;
        }
        if (kq == 0) {
#pragma unroll
            for (int t = 0; t < 8; ++t)
                aggr[(size_t)r * 128 + t * 16 + row] = colacc[t];
        }
    }
}

// ---- two-pass A: h[slot] = silu(A[s] + B[r] + d*w3), dist precomputed ------
__global__ __launch_bounds__(256) void k_msg1(
    const __bf16* __restrict__ AB, const int* __restrict__ csr_s,
    const int* __restrict__ csr_r, const float* __restrict__ dist,
    const float* __restrict__ w3, __bf16* __restrict__ h, int E)
{
    const int stride = gridDim.x * 256;
    const int total  = E * 4;
    for (int i = blockIdx.x * 256 + threadIdx.x; i < total; i += stride) {
        const int e = i >> 2;
        const int c = i & 3;
        const int s = csr_s[e], r = csr_r[e];
        const float d = dist[e];

        const __bf16* Ar = AB + (size_t)s * 256 + c * 32;
        const __bf16* Br = AB + (size_t)r * 256 + 128 + c * 32;
        const float*  wr = w3 + c * 32;
        __bf16* hw = h + (size_t)e * 128 + c * 32;

#pragma unroll
        for (int v = 0; v < 4; ++v) {
            bf16x8 a = *(const bf16x8*)(Ar + v * 8);
            bf16x8 b = *(const bf16x8*)(Br + v * 8);
            float4 w0 = *(const float4*)(wr + v * 8);
            float4 w1 = *(const float4*)(wr + v * 8 + 4);
            bf16x8 o;
            o[0] = (__bf16)silu_f((float)a[0] + (float)b[0] + d * w0.x);
            o[1] = (__bf16)silu_f((float)a[1] + (float)b[1] + d * w0.y);
            o[2] = (__bf16)silu_f((float)a[2] + (float)b[2] + d * w0.z);
            o[3] = (__bf16)silu_f((float)a[3] + (float)b[3] + d * w0.w);
            o[4] = (__bf16)silu_f((float)a[4] + (float)b[4] + d * w1.x);
            o[5] = (__bf16)silu_f((float)a[5] + (float)b[5] + d * w1.y);
            o[6] = (__bf16)silu_f((float)a[6] + (float)b[6] + d * w1.z);
            o[7] = (__bf16)silu_f((float)a[7] + (float)b[7] + d * w1.w);
            *(bf16x8*)(hw + v * 8) = o;
        }
    }
}

// ---- two-pass B: wave-per-receiver-pair over contiguous h (r11, 126 us) ----
__global__ __launch_bounds__(256) void k_edge_r2(
    const __bf16* __restrict__ h, const int* __restrict__ offs,
    const int* __restrict__ counts, const float* __restrict__ W2,
    const float* __restrict__ b2, float* __restrict__ aggr, int N)
{
    __shared__ __bf16 wt[128 * 128];
    for (int idx = threadIdx.x; idx < 128 * 128; idx += 256) {
        int j = idx & 127, k = idx >> 7;
        wt[(j << 7) + ((((k >> 3) ^ (j & 7))) << 3) + (k & 7)] = (__bf16)W2[(k << 7) + j];
    }
    __syncthreads();

    const int lane = threadIdx.x & 63;
    const int row  = lane & 15;
    const int kq   = lane >> 4;
    const int wid  = threadIdx.x >> 6;
    const int wstep = gridDim.x * 4;
    const int npair = (N + 1) >> 1;

    float b2c[8];
#pragma unroll
    for (int t = 0; t < 8; ++t) b2c[t] = b2[t * 16 + row];

    for (int p = blockIdx.x * 4 + wid; p < npair; p += wstep) {
        const int r0 = 2 * p;
        const int r1 = 2 * p + 1;
        const int off0 = offs[r0], deg0 = counts[r0];
        int off1 = 0, deg1 = 0;
        if (r1 < N) { off1 = offs[r1]; deg1 = counts[r1]; }

        float ca0[8] = {0,0,0,0,0,0,0,0};
        float ca1[8] = {0,0,0,0,0,0,0,0};

        const int nt0 = (deg0 + 15) >> 4;
        const int nt1 = (deg1 + 15) >> 4;
        const int nt  = nt0 > nt1 ? nt0 : nt1;

        for (int tile = 0; tile < nt; ++tile) {
            const int el = tile * 16 + row;
            const int i0 = deg0 ? off0 + ((el < deg0) ? el : deg0 - 1) : 0;
            const int i1 = deg1 ? off1 + ((el < deg1) ? el : deg1 - 1) : 0;

            bf16x8 af0[4], af1[4];
#pragma unroll
            for (int c = 0; c < 4; ++c) {
                const int k0 = c * 32 + kq * 8;
                af0[c] = *(const bf16x8*)(h + (size_t)i0 * 128 + k0);
                af1[c] = *(const bf16x8*)(h + (size_t)i1 * 128 + k0);
            }

#pragma unroll
            for (int t = 0; t < 8; ++t) {
                const int j  = t * 16 + row;
                const int jb = j & 7;
                const __bf16* base = wt + (j << 7);
                f32x4 a0 = {}, a1 = {};
#pragma unroll
                for (int c = 0; c < 4; ++c) {
                    const int kb = c * 4 + kq;
                    bf16x8 b = *(const bf16x8*)(base + ((kb ^ jb) << 3));
                    a0 = MFMA16(af0[c], b, a0, 0, 0, 0);
                    a1 = MFMA16(af1[c], b, a1, 0, 0, 0);
                }
#pragma unroll
                for (int q = 0; q < 4; ++q) {
                    const int er = tile * 16 + kq * 4 + q;
                    if (er < deg0) ca0[t] += silu_f(a0[q] + b2c[t]);
                    if (er < deg1) ca1[t] += silu_f(a1[q] + b2c[t]);
                }
            }
        }

#pragma unroll
        for (int t = 0; t < 8; ++t) {
            float v0 = ca0[t], v1 = ca1[t];
            v0 += __shfl_xor(v0, 16, 64);
            v0 += __shfl_xor(v0, 32, 64);
            v1 += __shfl_xor(v1, 16, 64);
            v1 += __shfl_xor(v1, 32, 64);
            ca0[t] = v0; ca1[t] = v1;
        }
        if (kq == 0) {
#pragma unroll
            for (int t = 0; t < 8; ++t)
                aggr[(size_t)r0 * 128 + t * 16 + row] = ca0[t];
            if (r1 < N) {
#pragma unroll
                for (int t = 0; t < 8; ++t)
                    aggr[(size_t)r1 * 128 + t * 16 + row] = ca1[t];
            }
        }
    }
}

// -------- phase 3: u = silu(x@U1a + aggr@U1b + c1), bf16, IN PLACE over aggr
__global__ __launch_bounds__(256) void k_node2(
    const float* __restrict__ x, const float* __restrict__ aggr,
    const float* __restrict__ U1, const float* __restrict__ c1,
    __bf16* __restrict__ u, int N, int ngroups)
{
    __shared__ __bf16 wt[128 * 256];
    for (int idx = threadIdx.x; idx < 128 * 256; idx += 256) {
        int j = idx & 127, k = idx >> 7;
        wt[(j << 8) + ((((k >> 3) ^ (j & 7))) << 3) + (k & 7)] = (__bf16)U1[(k << 7) + j];
    }
    __syncthreads();

    const int lane = threadIdx.x & 63;
    const int row  = lane & 15;
    const int kq   = lane >> 4;

    for (int g = blockIdx.x; g < ngroups; g += gridDim.x) {
        const int row0 = g * 64 + (threadIdx.x >> 6) * 16;
        int m = row0 + row; if (m >= N) m = N - 1;

        bf16x8 afr[8];
#pragma unroll
        for (int c = 0; c < 8; ++c) {
            const int k0 = (c & 3) * 32 + kq * 8;
            const float* src = (c < 4) ? (x + (size_t)m * 128 + k0)
                                       : (aggr + (size_t)m * 128 + k0);
            float4 a0 = *(const float4*)(src);
            float4 a1 = *(const float4*)(src + 4);
            bf16x8 af;
            af[0]=(__bf16)a0.x; af[1]=(__bf16)a0.y; af[2]=(__bf16)a0.z; af[3]=(__bf16)a0.w;
            af[4]=(__bf16)a1.x; af[5]=(__bf16)a1.y; af[6]=(__bf16)a1.z; af[7]=(__bf16)a1.w;
            afr[c] = af;
        }

        f32x4 acc[8] = {};
#pragma unroll
        for (int t = 0; t < 8; ++t) {
            const int j  = t * 16 + row;
            const int jb = j & 7;
            const __bf16* base = wt + (j << 8);
#pragma unroll
            for (int c = 0; c < 8; ++c) {
                const int kb = c * 4 + kq;
                bf16x8 b = *(const bf16x8*)(base + ((kb ^ jb) << 3));
                acc[t] = MFMA16(afr[c], b, acc[t], 0, 0, 0);
            }
        }

#pragma unroll
        for (int t = 0; t < 8; ++t) {
            const int col = t * 16 + row;
            const float cc = c1[col];
#pragma unroll
            for (int q = 0; q < 4; ++q) {
                const int gr = row0 + kq * 4 + q;
                if (gr < N) u[(size_t)gr * 256 + col] = (__bf16)silu_f(acc[t][q] + cc);
            }
        }
    }
}

// ---------------- phase 4: out = u@U2 + c2 (overwrites AB in d_out) ---------
__global__ __launch_bounds__(256) void k_node3(
    const __bf16* __restrict__ u, const float* __restrict__ U2,
    const float* __restrict__ c2, float* __restrict__ out, int N, int ngroups)
{
    __shared__ __bf16 wt[128 * 128];
    for (int idx = threadIdx.x; idx < 128 * 128; idx += 256) {
        int j = idx & 127, k = idx >> 7;
        wt[(j << 7) + ((((k >> 3) ^ (j & 7))) << 3) + (k & 7)] = (__bf16)U2[(k << 7) + j];
    }
    __syncthreads();

    const int lane = threadIdx.x & 63;
    const int row  = lane & 15;
    const int kq   = lane >> 4;

    for (int g = blockIdx.x; g < ngroups; g += gridDim.x) {
        const int row0 = g * 64 + (threadIdx.x >> 6) * 16;
        int m = row0 + row; if (m >= N) m = N - 1;

        bf16x8 afr[4];
#pragma unroll
        for (int c = 0; c < 4; ++c) {
            const int k0 = c * 32 + kq * 8;
            afr[c] = *(const bf16x8*)(u + (size_t)m * 256 + k0);
        }

        f32x4 acc[8] = {};
#pragma unroll
        for (int t = 0; t < 8; ++t) {
            const int j  = t * 16 + row;
            const int jb = j & 7;
            const __bf16* base = wt + (j << 7);
#pragma unroll
            for (int c = 0; c < 4; ++c) {
                const int kb = c * 4 + kq;
                bf16x8 b = *(const bf16x8*)(base + ((kb ^ jb) << 3));
                acc[t] = MFMA16(afr[c], b, acc[t], 0, 0, 0);
            }
        }

#pragma unroll
        for (int t = 0; t < 8; ++t) {
            const int col = t * 16 + row;
            const float cc = c2[col];
#pragma unroll
            for (int q = 0; q < 4; ++q) {
                const int gr = row0 + kq * 4 + q;
                if (gr < N) out[(size_t)gr * 128 + col] = acc[t][q] + cc;
            }
        }
    }
}

extern "C" void kernel_launch(void* const* d_in, const int* in_sizes, int n_in,
                              void* d_out, int out_size, void* d_ws, size_t ws_size,
                              hipStream_t stream) {
    (void)n_in; (void)out_size;
    const float* x   = (const float*)d_in[0];
    const float* pos = (const float*)d_in[1];
    const int*   ei  = (const int*)d_in[2];
    const float* W1  = (const float*)d_in[3];
    const float* b1  = (const float*)d_in[4];
    const float* W2  = (const float*)d_in[5];
    const float* b2  = (const float*)d_in[6];
    const float* U1  = (const float*)d_in[7];
    const float* c1  = (const float*)d_in[8];
    const float* U2  = (const float*)d_in[9];
    const float* c2  = (const float*)d_in[10];

    const int N = in_sizes[0] / 128;
    const int E = in_sizes[2] / 2;

    // ---- workspace layout (16B-aligned slabs) ----
    const size_t aggr_b = (size_t)N * 128 * sizeof(float);
    const size_t Ni_b   = (((size_t)N * 4) + 15) & ~(size_t)15;
    const size_t E_b    = (((size_t)E * 4) + 15) & ~(size_t)15;
    size_t off = 0;
    char* base = (char*)d_ws;
    float* aggr   = (float*)(base + off); off += aggr_b;
    int*   flag   = (int*)  (base + off); off += 16;
    int*   counts = (int*)  (base + off); off += Ni_b;
    int*   offs   = (int*)  (base + off); off += Ni_b;
    int*   cursor = (int*)  (base + off); off += Ni_b;
    int*   parts  = (int*)  (base + off); off += 256 * 4;
    int*   csr_s  = (int*)  (base + off); off += E_b;
    int*   csr_r  = (int*)  (base + off); off += E_b;
    float* dist   = (float*)(base + off); off += E_b;
    const size_t need_csr = off;
    off = (off + 63) & ~(size_t)63;
    __bf16* h = (__bf16*)(base + off); off += (size_t)E * 128 * 2;
    const size_t need_h = off;

    __bf16* u  = (__bf16*)d_ws;        // row stride 256 elem, aliases aggr
    __bf16* AB = (__bf16*)d_out;       // N*256 bf16 == out_nbytes

    const int nblk_scan = (N + 511) / 512;
    const bool csr_ok = (ws_size >= need_csr) && (nblk_scan <= 256);
    if (ws_size < aggr_b + 16 || !csr_ok) return;

    // runtime register check: use fused only if it stayed under the cliff
    hipFuncAttributes fa{};
    const bool fused_ok =
        (hipFuncGetAttributes(&fa, (const void*)k_edge_f3) == hipSuccess) &&
        (fa.numRegs <= 124);
    const bool twopass = !fused_ok && (ws_size >= need_h);
    if (!fused_ok && !twopass) return;

    const int ng_nodes = (N + 63) / 64;
    const int grid_n   = ng_nodes < 512 ? ng_nodes : 512;
    const int grid_E   = (E + 255) / 256;
    const int grid_Nt  = (N + 255) / 256;
    const int grid_m   = ((E * 4 + 255) / 256) < 2048 ? ((E * 4 + 255) / 256) : 2048;
    const int npair    = (N + 1) / 2;
    const int grid_p   = ((npair + 3) / 4) < 2048 ? ((npair + 3) / 4) : 2048;
    const int grid_f   = ((N + 3) / 4) < 2048 ? ((N + 3) / 4) : 2048;

    k_detect<<<1, 256, 0, stream>>>(ei, flag);
    k_node1<<<grid_n, 256, 0, stream>>>(x, W1, b1, AB, N, ng_nodes);

    hipMemsetAsync(counts, 0, (size_t)N * 4, stream);
    k_hist   <<<grid_E, 256, 0, stream>>>(ei, flag, counts, E);
    k_scan1  <<<nblk_scan, 256, 0, stream>>>(counts, offs, parts, N);
    k_scan2  <<<1, 256, 0, stream>>>(parts, nblk_scan);
    k_scan3  <<<grid_Nt, 256, 0, stream>>>(offs, parts, cursor, N);
    k_scatter<<<grid_E, 256, 0, stream>>>(ei, flag, pos, cursor,
                                          csr_s, csr_r, dist, E);

    if (fused_ok) {
        k_edge_f3<<<grid_f, 256, 0, stream>>>(AB, csr_s, dist, offs, counts,
                                              W2, b2, W1 + 256 * 128, aggr, N);
    } else {
        k_msg1   <<<grid_m, 256, 0, stream>>>(AB, csr_s, csr_r, dist,
                                              W1 + 256 * 128, h, E);
        k_edge_r2<<<grid_p, 256, 0, stream>>>(h, offs, counts, W2, b2, aggr, N);
    }

    k_node2<<<grid_n, 256, 0, stream>>>(x, aggr, U1, c1, u, N, ng_nodes);
    k_node3<<<grid_n, 256, 0, stream>>>(u, U2, c2, (float*)d_out, N, ng_nodes);
}

// Round 15
// 421.658 us; speedup vs baseline: 1.0004x; 1.0004x over previous
//
#include <hip/hip_runtime.h>
#include <hip/hip_bf16.h>
#include <math.h>

typedef __bf16 bf16x8 __attribute__((ext_vector_type(8)));
typedef float  f32x4  __attribute__((ext_vector_type(4)));

#define MFMA16 __builtin_amdgcn_mfma_f32_16x16x32_bf16

__device__ __forceinline__ float silu_f(float v) {
    return v * __builtin_amdgcn_rcpf(1.0f + __expf(-v));
}

// LDS weight layout: Wt[j][k], bf16, 16B-chunk XOR swizzle:
// phys = j*K + (((k>>3) ^ (j&7))<<3) + (k&7)  -> ds_read_b128, 2-way max.

// ---- detector: is edge_index stored as int64 (odd words all zero)? ---------
__global__ void k_detect(const int* __restrict__ ei, int* __restrict__ flag) {
    __shared__ int red[256];
    int v = 0;
#pragma unroll
    for (int j = 0; j < 4; ++j) v |= ei[2 * (threadIdx.x * 4 + j) + 1];
    red[threadIdx.x] = v;
    __syncthreads();
    for (int s = 128; s > 0; s >>= 1) {
        if (threadIdx.x < s) red[threadIdx.x] |= red[threadIdx.x + s];
        __syncthreads();
    }
    if (threadIdx.x == 0) *flag = (red[0] == 0) ? 1 : 0;
}

// ---- CSR build --------------------------------------------------------------
__global__ __launch_bounds__(256) void k_hist(
    const int* __restrict__ ei, const int* __restrict__ flag,
    int* __restrict__ counts, int E)
{
    int e = blockIdx.x * 256 + threadIdx.x;
    if (e >= E) return;
    const int is64 = *flag;
    int r = is64 ? ei[2 * E + 2 * e] : ei[E + e];
    atomicAdd(&counts[r], 1);
}

__global__ __launch_bounds__(256) void k_scan1(
    const int* __restrict__ counts, int* __restrict__ offsets,
    int* __restrict__ partials, int N)
{
    __shared__ int pairv[256];
    __shared__ int buf[256];
    const int t = threadIdx.x;
    const int base = blockIdx.x * 512;
    int a = (base + 2 * t     < N) ? counts[base + 2 * t]     : 0;
    int b = (base + 2 * t + 1 < N) ? counts[base + 2 * t + 1] : 0;
    pairv[t] = a + b;
    buf[t]   = a + b;
    __syncthreads();
    for (int d = 1; d < 256; d <<= 1) {
        int v = buf[t];
        int w = (t >= d) ? buf[t - d] : 0;
        __syncthreads();
        buf[t] = v + w;
        __syncthreads();
    }
    int excl = buf[t] - pairv[t];
    if (base + 2 * t     < N) offsets[base + 2 * t]     = excl;
    if (base + 2 * t + 1 < N) offsets[base + 2 * t + 1] = excl + a;
    if (t == 255) partials[blockIdx.x] = buf[255];
}

__global__ void k_scan2(int* __restrict__ partials, int nblk) {
    __shared__ int buf[256];
    const int t = threadIdx.x;
    int v0 = (t < nblk) ? partials[t] : 0;
    buf[t] = v0;
    __syncthreads();
    for (int d = 1; d < 256; d <<= 1) {
        int v = buf[t];
        int w = (t >= d) ? buf[t - d] : 0;
        __syncthreads();
        buf[t] = v + w;
        __syncthreads();
    }
    if (t < nblk) partials[t] = buf[t] - v0;   // exclusive
}

__global__ __launch_bounds__(256) void k_scan3(
    int* __restrict__ offsets, const int* __restrict__ partials,
    int* __restrict__ cursor, int N)
{
    int i = blockIdx.x * 256 + threadIdx.x;
    if (i >= N) return;
    int v = offsets[i] + partials[i >> 9];
    offsets[i] = v;
    cursor[i]  = v;
}

// scatter + per-edge distance precompute (kills pos-gather chains downstream)
__global__ __launch_bounds__(256) void k_scatter(
    const int* __restrict__ ei, const int* __restrict__ flag,
    const float* __restrict__ pos, int* __restrict__ cursor,
    int* __restrict__ csr_s, int* __restrict__ csr_r,
    float* __restrict__ dist, int E)
{
    int e = blockIdx.x * 256 + threadIdx.x;
    if (e >= E) return;
    const int is64 = *flag;
    int s, r;
    if (is64) { s = ei[2 * e]; r = ei[2 * E + 2 * e]; }
    else      { s = ei[e];     r = ei[E + e];         }
    float dx = pos[3 * s]     - pos[3 * r];
    float dy = pos[3 * s + 1] - pos[3 * r + 1];
    float dz = pos[3 * s + 2] - pos[3 * r + 2];
    float d  = sqrtf(dx * dx + dy * dy + dz * dz);
    int slot = atomicAdd(&cursor[r], 1);
    csr_s[slot] = s;
    csr_r[slot] = r;
    dist[slot]  = d;
}

// ---- phase 1: AB[n][0:128]=bf16(x@W1a + b1), AB[n][128:256]=bf16(x@W1b) ----
__global__ __launch_bounds__(256) void k_node1(
    const float* __restrict__ x, const float* __restrict__ W1,
    const float* __restrict__ b1, __bf16* __restrict__ AB, int N, int ngroups)
{
    __shared__ __bf16 wt[256 * 128];
    for (int idx = threadIdx.x; idx < 256 * 128; idx += 256) {
        int j = idx & 255, k = idx >> 8;
        float w = (j < 128) ? W1[(k << 7) + j] : W1[((k + 128) << 7) + (j - 128)];
        wt[(j << 7) + ((((k >> 3) ^ (j & 7))) << 3) + (k & 7)] = (__bf16)w;
    }
    __syncthreads();

    const int lane = threadIdx.x & 63;
    const int row  = lane & 15;
    const int kq   = lane >> 4;

    for (int g = blockIdx.x; g < ngroups; g += gridDim.x) {
        const int row0 = g * 64 + (threadIdx.x >> 6) * 16;
        int m = row0 + row; if (m >= N) m = N - 1;
        const float* xr = x + (size_t)m * 128;

        bf16x8 afr[4];
#pragma unroll
        for (int c = 0; c < 4; ++c) {
            const int k0 = c * 32 + kq * 8;
            float4 a0 = *(const float4*)(xr + k0);
            float4 a1 = *(const float4*)(xr + k0 + 4);
            bf16x8 af;
            af[0]=(__bf16)a0.x; af[1]=(__bf16)a0.y; af[2]=(__bf16)a0.z; af[3]=(__bf16)a0.w;
            af[4]=(__bf16)a1.x; af[5]=(__bf16)a1.y; af[6]=(__bf16)a1.z; af[7]=(__bf16)a1.w;
            afr[c] = af;
        }

        f32x4 acc[16] = {};
#pragma unroll
        for (int t = 0; t < 16; ++t) {
            const int j  = t * 16 + row;
            const int jb = j & 7;
            const __bf16* base = wt + (j << 7);
#pragma unroll
            for (int c = 0; c < 4; ++c) {
                const int kb = c * 4 + kq;
                bf16x8 b = *(const bf16x8*)(base + ((kb ^ jb) << 3));
                acc[t] = MFMA16(afr[c], b, acc[t], 0, 0, 0);
            }
        }

#pragma unroll
        for (int t = 0; t < 16; ++t) {
            const int col = t * 16 + row;
            const float bb = (col < 128) ? b1[col] : 0.0f;
#pragma unroll
            for (int q = 0; q < 4; ++q) {
                const int gr = row0 + kq * 4 + q;
                if (gr < N) AB[(size_t)gr * 256 + col] = (__bf16)(acc[t][q] + bb);
            }
        }
    }
}

// ---- FUSED edge phase v4: COLUMN-SPLIT wave-per-receiver, no atomics -------
// Two waves per receiver; wave half hf owns output cols [64*hf, 64*hf+64).
// acc[4]=16 VGPR + colacc[4] by construction; B-row in per-wave LDS slot;
// first layer recomputed per wave (AB is L2/L3-resident -> cheap).
__global__ __launch_bounds__(256) void k_edge_f4(
    const __bf16* __restrict__ AB, const int* __restrict__ csr_s,
    const float* __restrict__ dist, const int* __restrict__ offs,
    const int* __restrict__ counts, const float* __restrict__ W2,
    const float* __restrict__ b2, const float* __restrict__ w3,
    float* __restrict__ aggr, int N)
{
    __shared__ __bf16 wt[128 * 128];     // 32 KB W2^T swizzled
    __shared__ float  w3s[128];
    __shared__ float  b2s[128];
    __shared__ __bf16 bsl[4][128];       // per-wave B-row slot (256 B each)
    for (int idx = threadIdx.x; idx < 128 * 128; idx += 256) {
        int j = idx & 127, k = idx >> 7;
        wt[(j << 7) + ((((k >> 3) ^ (j & 7))) << 3) + (k & 7)] = (__bf16)W2[(k << 7) + j];
    }
    for (int i = threadIdx.x; i < 128; i += 256) { w3s[i] = w3[i]; b2s[i] = b2[i]; }
    __syncthreads();

    const int lane = threadIdx.x & 63;
    const int row  = lane & 15;
    const int kq   = lane >> 4;
    const int wid  = threadIdx.x >> 6;
    const int wstep = gridDim.x * 4;
    const int nslot = 2 * N;

    for (int v = blockIdx.x * 4 + wid; v < nslot; v += wstep) {
        const int r  = v >> 1;
        const int hf = v & 1;                 // column half
        const int off = offs[r];
        const int deg = counts[r];

        // stage B[r] (full row, needed for first layer) into wave's LDS slot
        if (lane < 16)
            *(bf16x8*)(&bsl[wid][lane * 8]) =
                *(const bf16x8*)(AB + (size_t)r * 256 + 128 + lane * 8);

        float colacc[4] = {0, 0, 0, 0};

        const int ntile = (deg + 15) >> 4;
        for (int tile = 0; tile < ntile; ++tile) {
            const int el  = tile * 16 + row;
            const int idx = off + ((el < deg) ? el : (deg - 1));
            const int s   = csr_s[idx];
            const float d = dist[idx];

            f32x4 acc[4] = {};
#pragma unroll
            for (int c = 0; c < 4; ++c) {
                const int k0 = c * 32 + kq * 8;
                bf16x8 a  = *(const bf16x8*)(AB + (size_t)s * 256 + k0);
                bf16x8 bb = *(const bf16x8*)(&bsl[wid][k0]);
                float4 w0 = *(const float4*)(w3s + k0);
                float4 w1 = *(const float4*)(w3s + k0 + 4);
                bf16x8 af;
                af[0] = (__bf16)silu_f((float)a[0] + (float)bb[0] + d * w0.x);
                af[1] = (__bf16)silu_f((float)a[1] + (float)bb[1] + d * w0.y);
                af[2] = (__bf16)silu_f((float)a[2] + (float)bb[2] + d * w0.z);
                af[3] = (__bf16)silu_f((float)a[3] + (float)bb[3] + d * w0.w);
                af[4] = (__bf16)silu_f((float)a[4] + (float)bb[4] + d * w1.x);
                af[5] = (__bf16)silu_f((float)a[5] + (float)bb[5] + d * w1.y);
                af[6] = (__bf16)silu_f((float)a[6] + (float)bb[6] + d * w1.z);
                af[7] = (__bf16)silu_f((float)a[7] + (float)bb[7] + d * w1.w);
                const int kb = c * 4 + kq;
#pragma unroll
                for (int t4 = 0; t4 < 4; ++t4) {
                    const int j  = (hf * 4 + t4) * 16 + row;
                    const int jb = j & 7;
                    bf16x8 b = *(const bf16x8*)(wt + (j << 7) + ((kb ^ jb) << 3));
                    acc[t4] = MFMA16(af, b, acc[t4], 0, 0, 0);
                }
            }

#pragma unroll
            for (int t4 = 0; t4 < 4; ++t4) {
                const float bb = b2s[(hf * 4 + t4) * 16 + row];
#pragma unroll
                for (int q = 0; q < 4; ++q) {
                    const int er = tile * 16 + kq * 4 + q;
                    if (er < deg) colacc[t4] += silu_f(acc[t4][q] + bb);
                }
            }
        }

#pragma unroll
        for (int t4 = 0; t4 < 4; ++t4) {
            float vv = colacc[t4];
            vv += __shfl_xor(vv, 16, 64);
            vv += __shfl_xor(vv, 32, 64);
            colacc[t4] = vv;
        }
        if (kq == 0) {
#pragma unroll
            for (int t4 = 0; t4 < 4; ++t4)
                aggr[(size_t)r * 128 + (hf * 4 + t4) * 16 + row] = colacc[t4];
        }
    }
}

// ---- two-pass A: h[slot] = silu(A[s] + B[r] + d*w3), dist precomputed ------
__global__ __launch_bounds__(256) void k_msg1(
    const __bf16* __restrict__ AB, const int* __restrict__ csr_s,
    const int* __restrict__ csr_r, const float* __restrict__ dist,
    const float* __restrict__ w3, __bf16* __restrict__ h, int E)
{
    const int stride = gridDim.x * 256;
    const int total  = E * 4;
    for (int i = blockIdx.x * 256 + threadIdx.x; i < total; i += stride) {
        const int e = i >> 2;
        const int c = i & 3;
        const int s = csr_s[e], r = csr_r[e];
        const float d = dist[e];

        const __bf16* Ar = AB + (size_t)s * 256 + c * 32;
        const __bf16* Br = AB + (size_t)r * 256 + 128 + c * 32;
        const float*  wr = w3 + c * 32;
        __bf16* hw = h + (size_t)e * 128 + c * 32;

#pragma unroll
        for (int v = 0; v < 4; ++v) {
            bf16x8 a = *(const bf16x8*)(Ar + v * 8);
            bf16x8 b = *(const bf16x8*)(Br + v * 8);
            float4 w0 = *(const float4*)(wr + v * 8);
            float4 w1 = *(const float4*)(wr + v * 8 + 4);
            bf16x8 o;
            o[0] = (__bf16)silu_f((float)a[0] + (float)b[0] + d * w0.x);
            o[1] = (__bf16)silu_f((float)a[1] + (float)b[1] + d * w0.y);
            o[2] = (__bf16)silu_f((float)a[2] + (float)b[2] + d * w0.z);
            o[3] = (__bf16)silu_f((float)a[3] + (float)b[3] + d * w0.w);
            o[4] = (__bf16)silu_f((float)a[4] + (float)b[4] + d * w1.x);
            o[5] = (__bf16)silu_f((float)a[5] + (float)b[5] + d * w1.y);
            o[6] = (__bf16)silu_f((float)a[6] + (float)b[6] + d * w1.z);
            o[7] = (__bf16)silu_f((float)a[7] + (float)b[7] + d * w1.w);
            *(bf16x8*)(hw + v * 8) = o;
        }
    }
}

// ---- two-pass B: wave-per-receiver-pair over contiguous h (r11, 126 us) ----
__global__ __launch_bounds__(256) void k_edge_r2(
    const __bf16* __restrict__ h, const int* __restrict__ offs,
    const int* __restrict__ counts, const float* __restrict__ W2,
    const float* __restrict__ b2, float* __restrict__ aggr, int N)
{
    __shared__ __bf16 wt[128 * 128];
    for (int idx = threadIdx.x; idx < 128 * 128; idx += 256) {
        int j = idx & 127, k = idx >> 7;
        wt[(j << 7) + ((((k >> 3) ^ (j & 7))) << 3) + (k & 7)] = (__bf16)W2[(k << 7) + j];
    }
    __syncthreads();

    const int lane = threadIdx.x & 63;
    const int row  = lane & 15;
    const int kq   = lane >> 4;
    const int wid  = threadIdx.x >> 6;
    const int wstep = gridDim.x * 4;
    const int npair = (N + 1) >> 1;

    float b2c[8];
#pragma unroll
    for (int t = 0; t < 8; ++t) b2c[t] = b2[t * 16 + row];

    for (int p = blockIdx.x * 4 + wid; p < npair; p += wstep) {
        const int r0 = 2 * p;
        const int r1 = 2 * p + 1;
        const int off0 = offs[r0], deg0 = counts[r0];
        int off1 = 0, deg1 = 0;
        if (r1 < N) { off1 = offs[r1]; deg1 = counts[r1]; }

        float ca0[8] = {0,0,0,0,0,0,0,0};
        float ca1[8] = {0,0,0,0,0,0,0,0};

        const int nt0 = (deg0 + 15) >> 4;
        const int nt1 = (deg1 + 15) >> 4;
        const int nt  = nt0 > nt1 ? nt0 : nt1;

        for (int tile = 0; tile < nt; ++tile) {
            const int el = tile * 16 + row;
            const int i0 = deg0 ? off0 + ((el < deg0) ? el : deg0 - 1) : 0;
            const int i1 = deg1 ? off1 + ((el < deg1) ? el : deg1 - 1) : 0;

            bf16x8 af0[4], af1[4];
#pragma unroll
            for (int c = 0; c < 4; ++c) {
                const int k0 = c * 32 + kq * 8;
                af0[c] = *(const bf16x8*)(h + (size_t)i0 * 128 + k0);
                af1[c] = *(const bf16x8*)(h + (size_t)i1 * 128 + k0);
            }

#pragma unroll
            for (int t = 0; t < 8; ++t) {
                const int j  = t * 16 + row;
                const int jb = j & 7;
                const __bf16* base = wt + (j << 7);
                f32x4 a0 = {}, a1 = {};
#pragma unroll
                for (int c = 0; c < 4; ++c) {
                    const int kb = c * 4 + kq;
                    bf16x8 b = *(const bf16x8*)(base + ((kb ^ jb) << 3));
                    a0 = MFMA16(af0[c], b, a0, 0, 0, 0);
                    a1 = MFMA16(af1[c], b, a1, 0, 0, 0);
                }
#pragma unroll
                for (int q = 0; q < 4; ++q) {
                    const int er = tile * 16 + kq * 4 + q;
                    if (er < deg0) ca0[t] += silu_f(a0[q] + b2c[t]);
                    if (er < deg1) ca1[t] += silu_f(a1[q] + b2c[t]);
                }
            }
        }

#pragma unroll
        for (int t = 0; t < 8; ++t) {
            float v0 = ca0[t], v1 = ca1[t];
            v0 += __shfl_xor(v0, 16, 64);
            v0 += __shfl_xor(v0, 32, 64);
            v1 += __shfl_xor(v1, 16, 64);
            v1 += __shfl_xor(v1, 32, 64);
            ca0[t] = v0; ca1[t] = v1;
        }
        if (kq == 0) {
#pragma unroll
            for (int t = 0; t < 8; ++t)
                aggr[(size_t)r0 * 128 + t * 16 + row] = ca0[t];
            if (r1 < N) {
#pragma unroll
                for (int t = 0; t < 8; ++t)
                    aggr[(size_t)r1 * 128 + t * 16 + row] = ca1[t];
            }
        }
    }
}

// -------- phase 3: u = silu(x@U1a + aggr@U1b + c1), bf16, IN PLACE over aggr
__global__ __launch_bounds__(256) void k_node2(
    const float* __restrict__ x, const float* __restrict__ aggr,
    const float* __restrict__ U1, const float* __restrict__ c1,
    __bf16* __restrict__ u, int N, int ngroups)
{
    __shared__ __bf16 wt[128 * 256];
    for (int idx = threadIdx.x; idx < 128 * 256; idx += 256) {
        int j = idx & 127, k = idx >> 7;
        wt[(j << 8) + ((((k >> 3) ^ (j & 7))) << 3) + (k & 7)] = (__bf16)U1[(k << 7) + j];
    }
    __syncthreads();

    const int lane = threadIdx.x & 63;
    const int row  = lane & 15;
    const int kq   = lane >> 4;

    for (int g = blockIdx.x; g < ngroups; g += gridDim.x) {
        const int row0 = g * 64 + (threadIdx.x >> 6) * 16;
        int m = row0 + row; if (m >= N) m = N - 1;

        bf16x8 afr[8];
#pragma unroll
        for (int c = 0; c < 8; ++c) {
            const int k0 = (c & 3) * 32 + kq * 8;
            const float* src = (c < 4) ? (x + (size_t)m * 128 + k0)
                                       : (aggr + (size_t)m * 128 + k0);
            float4 a0 = *(const float4*)(src);
            float4 a1 = *(const float4*)(src + 4);
            bf16x8 af;
            af[0]=(__bf16)a0.x; af[1]=(__bf16)a0.y; af[2]=(__bf16)a0.z; af[3]=(__bf16)a0.w;
            af[4]=(__bf16)a1.x; af[5]=(__bf16)a1.y; af[6]=(__bf16)a1.z; af[7]=(__bf16)a1.w;
            afr[c] = af;
        }

        f32x4 acc[8] = {};
#pragma unroll
        for (int t = 0; t < 8; ++t) {
            const int j  = t * 16 + row;
            const int jb = j & 7;
            const __bf16* base = wt + (j << 8);
#pragma unroll
            for (int c = 0; c < 8; ++c) {
                const int kb = c * 4 + kq;
                bf16x8 b = *(const bf16x8*)(base + ((kb ^ jb) << 3));
                acc[t] = MFMA16(afr[c], b, acc[t], 0, 0, 0);
            }
        }

#pragma unroll
        for (int t = 0; t < 8; ++t) {
            const int col = t * 16 + row;
            const float cc = c1[col];
#pragma unroll
            for (int q = 0; q < 4; ++q) {
                const int gr = row0 + kq * 4 + q;
                if (gr < N) u[(size_t)gr * 256 + col] = (__bf16)silu_f(acc[t][q] + cc);
            }
        }
    }
}

// ---------------- phase 4: out = u@U2 + c2 (overwrites AB in d_out) ---------
__global__ __launch_bounds__(256) void k_node3(
    const __bf16* __restrict__ u, const float* __restrict__ U2,
    const float* __restrict__ c2, float* __restrict__ out, int N, int ngroups)
{
    __shared__ __bf16 wt[128 * 128];
    for (int idx = threadIdx.x; idx < 128 * 128; idx += 256) {
        int j = idx & 127, k = idx >> 7;
        wt[(j << 7) + ((((k >> 3) ^ (j & 7))) << 3) + (k & 7)] = (__bf16)U2[(k << 7) + j];
    }
    __syncthreads();

    const int lane = threadIdx.x & 63;
    const int row  = lane & 15;
    const int kq   = lane >> 4;

    for (int g = blockIdx.x; g < ngroups; g += gridDim.x) {
        const int row0 = g * 64 + (threadIdx.x >> 6) * 16;
        int m = row0 + row; if (m >= N) m = N - 1;

        bf16x8 afr[4];
#pragma unroll
        for (int c = 0; c < 4; ++c) {
            const int k0 = c * 32 + kq * 8;
            afr[c] = *(const bf16x8*)(u + (size_t)m * 256 + k0);
        }

        f32x4 acc[8] = {};
#pragma unroll
        for (int t = 0; t < 8; ++t) {
            const int j  = t * 16 + row;
            const int jb = j & 7;
            const __bf16* base = wt + (j << 7);
#pragma unroll
            for (int c = 0; c < 4; ++c) {
                const int kb = c * 4 + kq;
                bf16x8 b = *(const bf16x8*)(base + ((kb ^ jb) << 3));
                acc[t] = MFMA16(afr[c], b, acc[t], 0, 0, 0);
            }
        }

#pragma unroll
        for (int t = 0; t < 8; ++t) {
            const int col = t * 16 + row;
            const float cc = c2[col];
#pragma unroll
            for (int q = 0; q < 4; ++q) {
                const int gr = row0 + kq * 4 + q;
                if (gr < N) out[(size_t)gr * 128 + col] = acc[t][q] + cc;
            }
        }
    }
}

extern "C" void kernel_launch(void* const* d_in, const int* in_sizes, int n_in,
                              void* d_out, int out_size, void* d_ws, size_t ws_size,
                              hipStream_t stream) {
    (void)n_in; (void)out_size;
    const float* x   = (const float*)d_in[0];
    const float* pos = (const float*)d_in[1];
    const int*   ei  = (const int*)d_in[2];
    const float* W1  = (const float*)d_in[3];
    const float* b1  = (const float*)d_in[4];
    const float* W2  = (const float*)d_in[5];
    const float* b2  = (const float*)d_in[6];
    const float* U1  = (const float*)d_in[7];
    const float* c1  = (const float*)d_in[8];
    const float* U2  = (const float*)d_in[9];
    const float* c2  = (const float*)d_in[10];

    const int N = in_sizes[0] / 128;
    const int E = in_sizes[2] / 2;

    // ---- workspace layout (16B-aligned slabs) ----
    const size_t aggr_b = (size_t)N * 128 * sizeof(float);
    const size_t Ni_b   = (((size_t)N * 4) + 15) & ~(size_t)15;
    const size_t E_b    = (((size_t)E * 4) + 15) & ~(size_t)15;
    size_t off = 0;
    char* base = (char*)d_ws;
    float* aggr   = (float*)(base + off); off += aggr_b;
    int*   flag   = (int*)  (base + off); off += 16;
    int*   counts = (int*)  (base + off); off += Ni_b;
    int*   offs   = (int*)  (base + off); off += Ni_b;
    int*   cursor = (int*)  (base + off); off += Ni_b;
    int*   parts  = (int*)  (base + off); off += 256 * 4;
    int*   csr_s  = (int*)  (base + off); off += E_b;
    int*   csr_r  = (int*)  (base + off); off += E_b;
    float* dist   = (float*)(base + off); off += E_b;
    const size_t need_csr = off;
    off = (off + 63) & ~(size_t)63;
    __bf16* h = (__bf16*)(base + off); off += (size_t)E * 128 * 2;
    const size_t need_h = off;

    __bf16* u  = (__bf16*)d_ws;        // row stride 256 elem, aliases aggr
    __bf16* AB = (__bf16*)d_out;       // N*256 bf16 == out_nbytes

    const int nblk_scan = (N + 511) / 512;
    const bool csr_ok = (ws_size >= need_csr) && (nblk_scan <= 256);
    if (ws_size < aggr_b + 16 || !csr_ok) return;

    // runtime register check: use fused only if it stayed under the cliff
    hipFuncAttributes fa{};
    const bool fused_ok =
        (hipFuncGetAttributes(&fa, (const void*)k_edge_f4) == hipSuccess) &&
        (fa.numRegs <= 124);
    const bool twopass = !fused_ok && (ws_size >= need_h);
    if (!fused_ok && !twopass) return;

    const int ng_nodes = (N + 63) / 64;
    const int grid_n   = ng_nodes < 512 ? ng_nodes : 512;
    const int grid_E   = (E + 255) / 256;
    const int grid_Nt  = (N + 255) / 256;
    const int grid_m   = ((E * 4 + 255) / 256) < 2048 ? ((E * 4 + 255) / 256) : 2048;
    const int npair    = (N + 1) / 2;
    const int grid_p   = ((npair + 3) / 4) < 2048 ? ((npair + 3) / 4) : 2048;
    const int nslot    = 2 * N;
    const int grid_f   = ((nslot + 3) / 4) < 2048 ? ((nslot + 3) / 4) : 2048;

    k_detect<<<1, 256, 0, stream>>>(ei, flag);
    k_node1<<<grid_n, 256, 0, stream>>>(x, W1, b1, AB, N, ng_nodes);

    hipMemsetAsync(counts, 0, (size_t)N * 4, stream);
    k_hist   <<<grid_E, 256, 0, stream>>>(ei, flag, counts, E);
    k_scan1  <<<nblk_scan, 256, 0, stream>>>(counts, offs, parts, N);
    k_scan2  <<<1, 256, 0, stream>>>(parts, nblk_scan);
    k_scan3  <<<grid_Nt, 256, 0, stream>>>(offs, parts, cursor, N);
    k_scatter<<<grid_E, 256, 0, stream>>>(ei, flag, pos, cursor,
                                          csr_s, csr_r, dist, E);

    if (fused_ok) {
        k_edge_f4<<<grid_f, 256, 0, stream>>>(AB, csr_s, dist, offs, counts,
                                              W2, b2, W1 + 256 * 128, aggr, N);
    } else {
        k_msg1   <<<grid_m, 256, 0, stream>>>(AB, csr_s, csr_r, dist,
                                              W1 + 256 * 128, h, E);
        k_edge_r2<<<grid_p, 256, 0, stream>>>(h, offs, counts, W2, b2, aggr, N);
    }

    k_node2<<<grid_n, 256, 0, stream>>>(x, aggr, U1, c1, u, N, ng_nodes);
    k_node3<<<grid_n, 256, 0, stream>>>(u, U2, c2, (float*)d_out, N, ng_nodes);
}

// Round 16
// 391.532 us; speedup vs baseline: 1.0774x; 1.0769x over previous
//
#include <hip/hip_runtime.h>
#include <hip/hip_bf16.h>
#include <math.h>

typedef __bf16 bf16x8 __attribute__((ext_vector_type(8)));
typedef float  f32x4  __attribute__((ext_vector_type(4)));

#define MFMA16 __builtin_amdgcn_mfma_f32_16x16x32_bf16

__device__ __forceinline__ float silu_f(float v) {
    return v * __builtin_amdgcn_rcpf(1.0f + __expf(-v));
}

// LDS weight layout: Wt[j][k], bf16, 16B-chunk XOR swizzle:
// phys = j*K + (((k>>3) ^ (j&7))<<3) + (k&7)  -> ds_read_b128, 2-way max.

// ---- detector: is edge_index stored as int64 (odd words all zero)? ---------
__global__ void k_detect(const int* __restrict__ ei, int* __restrict__ flag) {
    __shared__ int red[256];
    int v = 0;
#pragma unroll
    for (int j = 0; j < 4; ++j) v |= ei[2 * (threadIdx.x * 4 + j) + 1];
    red[threadIdx.x] = v;
    __syncthreads();
    for (int s = 128; s > 0; s >>= 1) {
        if (threadIdx.x < s) red[threadIdx.x] |= red[threadIdx.x + s];
        __syncthreads();
    }
    if (threadIdx.x == 0) *flag = (red[0] == 0) ? 1 : 0;
}

// ---- CSR build --------------------------------------------------------------
__global__ __launch_bounds__(256) void k_hist(
    const int* __restrict__ ei, const int* __restrict__ flag,
    int* __restrict__ counts, int E)
{
    int e = blockIdx.x * 256 + threadIdx.x;
    if (e >= E) return;
    const int is64 = *flag;
    int r = is64 ? ei[2 * E + 2 * e] : ei[E + e];
    atomicAdd(&counts[r], 1);
}

__global__ __launch_bounds__(256) void k_scan1(
    const int* __restrict__ counts, int* __restrict__ offsets,
    int* __restrict__ partials, int N)
{
    __shared__ int pairv[256];
    __shared__ int buf[256];
    const int t = threadIdx.x;
    const int base = blockIdx.x * 512;
    int a = (base + 2 * t     < N) ? counts[base + 2 * t]     : 0;
    int b = (base + 2 * t + 1 < N) ? counts[base + 2 * t + 1] : 0;
    pairv[t] = a + b;
    buf[t]   = a + b;
    __syncthreads();
    for (int d = 1; d < 256; d <<= 1) {
        int v = buf[t];
        int w = (t >= d) ? buf[t - d] : 0;
        __syncthreads();
        buf[t] = v + w;
        __syncthreads();
    }
    int excl = buf[t] - pairv[t];
    if (base + 2 * t     < N) offsets[base + 2 * t]     = excl;
    if (base + 2 * t + 1 < N) offsets[base + 2 * t + 1] = excl + a;
    if (t == 255) partials[blockIdx.x] = buf[255];
}

__global__ void k_scan2(int* __restrict__ partials, int nblk) {
    __shared__ int buf[256];
    const int t = threadIdx.x;
    int v0 = (t < nblk) ? partials[t] : 0;
    buf[t] = v0;
    __syncthreads();
    for (int d = 1; d < 256; d <<= 1) {
        int v = buf[t];
        int w = (t >= d) ? buf[t - d] : 0;
        __syncthreads();
        buf[t] = v + w;
        __syncthreads();
    }
    if (t < nblk) partials[t] = buf[t] - v0;   // exclusive
}

__global__ __launch_bounds__(256) void k_scan3(
    int* __restrict__ offsets, const int* __restrict__ partials,
    int* __restrict__ cursor, int N)
{
    int i = blockIdx.x * 256 + threadIdx.x;
    if (i >= N) return;
    int v = offsets[i] + partials[i >> 9];
    offsets[i] = v;
    cursor[i]  = v;
}

// scatter + per-edge distance precompute (kills pos-gather chains downstream)
__global__ __launch_bounds__(256) void k_scatter(
    const int* __restrict__ ei, const int* __restrict__ flag,
    const float* __restrict__ pos, int* __restrict__ cursor,
    int* __restrict__ csr_s, int* __restrict__ csr_r,
    float* __restrict__ dist, int E)
{
    int e = blockIdx.x * 256 + threadIdx.x;
    if (e >= E) return;
    const int is64 = *flag;
    int s, r;
    if (is64) { s = ei[2 * e]; r = ei[2 * E + 2 * e]; }
    else      { s = ei[e];     r = ei[E + e];         }
    float dx = pos[3 * s]     - pos[3 * r];
    float dy = pos[3 * s + 1] - pos[3 * r + 1];
    float dz = pos[3 * s + 2] - pos[3 * r + 2];
    float d  = sqrtf(dx * dx + dy * dy + dz * dz);
    int slot = atomicAdd(&cursor[r], 1);
    csr_s[slot] = s;
    csr_r[slot] = r;
    dist[slot]  = d;
}

// ---- phase 1: AB[n][0:128]=bf16(x@W1a + b1), AB[n][128:256]=bf16(x@W1b) ----
__global__ __launch_bounds__(256) void k_node1(
    const float* __restrict__ x, const float* __restrict__ W1,
    const float* __restrict__ b1, __bf16* __restrict__ AB, int N, int ngroups)
{
    __shared__ __bf16 wt[256 * 128];
    for (int idx = threadIdx.x; idx < 256 * 128; idx += 256) {
        int j = idx & 255, k = idx >> 8;
        float w = (j < 128) ? W1[(k << 7) + j] : W1[((k + 128) << 7) + (j - 128)];
        wt[(j << 7) + ((((k >> 3) ^ (j & 7))) << 3) + (k & 7)] = (__bf16)w;
    }
    __syncthreads();

    const int lane = threadIdx.x & 63;
    const int row  = lane & 15;
    const int kq   = lane >> 4;

    for (int g = blockIdx.x; g < ngroups; g += gridDim.x) {
        const int row0 = g * 64 + (threadIdx.x >> 6) * 16;
        int m = row0 + row; if (m >= N) m = N - 1;
        const float* xr = x + (size_t)m * 128;

        bf16x8 afr[4];
#pragma unroll
        for (int c = 0; c < 4; ++c) {
            const int k0 = c * 32 + kq * 8;
            float4 a0 = *(const float4*)(xr + k0);
            float4 a1 = *(const float4*)(xr + k0 + 4);
            bf16x8 af;
            af[0]=(__bf16)a0.x; af[1]=(__bf16)a0.y; af[2]=(__bf16)a0.z; af[3]=(__bf16)a0.w;
            af[4]=(__bf16)a1.x; af[5]=(__bf16)a1.y; af[6]=(__bf16)a1.z; af[7]=(__bf16)a1.w;
            afr[c] = af;
        }

        f32x4 acc[16] = {};
#pragma unroll
        for (int t = 0; t < 16; ++t) {
            const int j  = t * 16 + row;
            const int jb = j & 7;
            const __bf16* base = wt + (j << 7);
#pragma unroll
            for (int c = 0; c < 4; ++c) {
                const int kb = c * 4 + kq;
                bf16x8 b = *(const bf16x8*)(base + ((kb ^ jb) << 3));
                acc[t] = MFMA16(afr[c], b, acc[t], 0, 0, 0);
            }
        }

#pragma unroll
        for (int t = 0; t < 16; ++t) {
            const int col = t * 16 + row;
            const float bb = (col < 128) ? b1[col] : 0.0f;
#pragma unroll
            for (int q = 0; q < 4; ++q) {
                const int gr = row0 + kq * 4 + q;
                if (gr < N) AB[(size_t)gr * 256 + col] = (__bf16)(acc[t][q] + bb);
            }
        }
    }
}

// ---- FUSED edge phase v4: COLUMN-SPLIT wave-per-receiver, no atomics -------
// Two waves per receiver; wave half hf owns output cols [64*hf, 64*hf+64).
// acc[4]=16 VGPR + colacc[4] by construction; B-row in per-wave LDS slot;
// first layer recomputed per wave (AB is L2/L3-resident -> cheap).
// Launched UNCONDITIONALLY this round: rocprof VGPR_Count = ground truth.
__global__ __launch_bounds__(256) void k_edge_f4(
    const __bf16* __restrict__ AB, const int* __restrict__ csr_s,
    const float* __restrict__ dist, const int* __restrict__ offs,
    const int* __restrict__ counts, const float* __restrict__ W2,
    const float* __restrict__ b2, const float* __restrict__ w3,
    float* __restrict__ aggr, int N)
{
    __shared__ __bf16 wt[128 * 128];     // 32 KB W2^T swizzled
    __shared__ float  w3s[128];
    __shared__ float  b2s[128];
    __shared__ __bf16 bsl[4][128];       // per-wave B-row slot (256 B each)
    for (int idx = threadIdx.x; idx < 128 * 128; idx += 256) {
        int j = idx & 127, k = idx >> 7;
        wt[(j << 7) + ((((k >> 3) ^ (j & 7))) << 3) + (k & 7)] = (__bf16)W2[(k << 7) + j];
    }
    for (int i = threadIdx.x; i < 128; i += 256) { w3s[i] = w3[i]; b2s[i] = b2[i]; }
    __syncthreads();

    const int lane = threadIdx.x & 63;
    const int row  = lane & 15;
    const int kq   = lane >> 4;
    const int wid  = threadIdx.x >> 6;
    const int wstep = gridDim.x * 4;
    const int nslot = 2 * N;

    for (int v = blockIdx.x * 4 + wid; v < nslot; v += wstep) {
        const int r  = v >> 1;
        const int hf = v & 1;                 // column half
        const int off = offs[r];
        const int deg = counts[r];

        // stage B[r] (full row, needed for first layer) into wave's LDS slot
        if (lane < 16)
            *(bf16x8*)(&bsl[wid][lane * 8]) =
                *(const bf16x8*)(AB + (size_t)r * 256 + 128 + lane * 8);

        float colacc[4] = {0, 0, 0, 0};

        const int ntile = (deg + 15) >> 4;
        for (int tile = 0; tile < ntile; ++tile) {
            const int el  = tile * 16 + row;
            const int idx = off + ((el < deg) ? el : (deg - 1));
            const int s   = csr_s[idx];
            const float d = dist[idx];

            f32x4 acc[4] = {};
#pragma unroll
            for (int c = 0; c < 4; ++c) {
                const int k0 = c * 32 + kq * 8;
                bf16x8 a  = *(const bf16x8*)(AB + (size_t)s * 256 + k0);
                bf16x8 bb = *(const bf16x8*)(&bsl[wid][k0]);
                float4 w0 = *(const float4*)(w3s + k0);
                float4 w1 = *(const float4*)(w3s + k0 + 4);
                bf16x8 af;
                af[0] = (__bf16)silu_f((float)a[0] + (float)bb[0] + d * w0.x);
                af[1] = (__bf16)silu_f((float)a[1] + (float)bb[1] + d * w0.y);
                af[2] = (__bf16)silu_f((float)a[2] + (float)bb[2] + d * w0.z);
                af[3] = (__bf16)silu_f((float)a[3] + (float)bb[3] + d * w0.w);
                af[4] = (__bf16)silu_f((float)a[4] + (float)bb[4] + d * w1.x);
                af[5] = (__bf16)silu_f((float)a[5] + (float)bb[5] + d * w1.y);
                af[6] = (__bf16)silu_f((float)a[6] + (float)bb[6] + d * w1.z);
                af[7] = (__bf16)silu_f((float)a[7] + (float)bb[7] + d * w1.w);
                const int kb = c * 4 + kq;
#pragma unroll
                for (int t4 = 0; t4 < 4; ++t4) {
                    const int j  = (hf * 4 + t4) * 16 + row;
                    const int jb = j & 7;
                    bf16x8 b = *(const bf16x8*)(wt + (j << 7) + ((kb ^ jb) << 3));
                    acc[t4] = MFMA16(af, b, acc[t4], 0, 0, 0);
                }
            }

#pragma unroll
            for (int t4 = 0; t4 < 4; ++t4) {
                const float bb = b2s[(hf * 4 + t4) * 16 + row];
#pragma unroll
                for (int q = 0; q < 4; ++q) {
                    const int er = tile * 16 + kq * 4 + q;
                    if (er < deg) colacc[t4] += silu_f(acc[t4][q] + bb);
                }
            }
        }

#pragma unroll
        for (int t4 = 0; t4 < 4; ++t4) {
            float vv = colacc[t4];
            vv += __shfl_xor(vv, 16, 64);
            vv += __shfl_xor(vv, 32, 64);
            colacc[t4] = vv;
        }
        if (kq == 0) {
#pragma unroll
            for (int t4 = 0; t4 < 4; ++t4)
                aggr[(size_t)r * 128 + (hf * 4 + t4) * 16 + row] = colacc[t4];
        }
    }
}

// -------- phase 3: u = silu(x@U1a + aggr@U1b + c1), bf16, IN PLACE over aggr
__global__ __launch_bounds__(256) void k_node2(
    const float* __restrict__ x, const float* __restrict__ aggr,
    const float* __restrict__ U1, const float* __restrict__ c1,
    __bf16* __restrict__ u, int N, int ngroups)
{
    __shared__ __bf16 wt[128 * 256];
    for (int idx = threadIdx.x; idx < 128 * 256; idx += 256) {
        int j = idx & 127, k = idx >> 7;
        wt[(j << 8) + ((((k >> 3) ^ (j & 7))) << 3) + (k & 7)] = (__bf16)U1[(k << 7) + j];
    }
    __syncthreads();

    const int lane = threadIdx.x & 63;
    const int row  = lane & 15;
    const int kq   = lane >> 4;

    for (int g = blockIdx.x; g < ngroups; g += gridDim.x) {
        const int row0 = g * 64 + (threadIdx.x >> 6) * 16;
        int m = row0 + row; if (m >= N) m = N - 1;

        bf16x8 afr[8];
#pragma unroll
        for (int c = 0; c < 8; ++c) {
            const int k0 = (c & 3) * 32 + kq * 8;
            const float* src = (c < 4) ? (x + (size_t)m * 128 + k0)
                                       : (aggr + (size_t)m * 128 + k0);
            float4 a0 = *(const float4*)(src);
            float4 a1 = *(const float4*)(src + 4);
            bf16x8 af;
            af[0]=(__bf16)a0.x; af[1]=(__bf16)a0.y; af[2]=(__bf16)a0.z; af[3]=(__bf16)a0.w;
            af[4]=(__bf16)a1.x; af[5]=(__bf16)a1.y; af[6]=(__bf16)a1.z; af[7]=(__bf16)a1.w;
            afr[c] = af;
        }

        f32x4 acc[8] = {};
#pragma unroll
        for (int t = 0; t < 8; ++t) {
            const int j  = t * 16 + row;
            const int jb = j & 7;
            const __bf16* base = wt + (j << 8);
#pragma unroll
            for (int c = 0; c < 8; ++c) {
                const int kb = c * 4 + kq;
                bf16x8 b = *(const bf16x8*)(base + ((kb ^ jb) << 3));
                acc[t] = MFMA16(afr[c], b, acc[t], 0, 0, 0);
            }
        }

#pragma unroll
        for (int t = 0; t < 8; ++t) {
            const int col = t * 16 + row;
            const float cc = c1[col];
#pragma unroll
            for (int q = 0; q < 4; ++q) {
                const int gr = row0 + kq * 4 + q;
                if (gr < N) u[(size_t)gr * 256 + col] = (__bf16)silu_f(acc[t][q] + cc);
            }
        }
    }
}

// ---------------- phase 4: out = u@U2 + c2 (overwrites AB in d_out) ---------
__global__ __launch_bounds__(256) void k_node3(
    const __bf16* __restrict__ u, const float* __restrict__ U2,
    const float* __restrict__ c2, float* __restrict__ out, int N, int ngroups)
{
    __shared__ __bf16 wt[128 * 128];
    for (int idx = threadIdx.x; idx < 128 * 128; idx += 256) {
        int j = idx & 127, k = idx >> 7;
        wt[(j << 7) + ((((k >> 3) ^ (j & 7))) << 3) + (k & 7)] = (__bf16)U2[(k << 7) + j];
    }
    __syncthreads();

    const int lane = threadIdx.x & 63;
    const int row  = lane & 15;
    const int kq   = lane >> 4;

    for (int g = blockIdx.x; g < ngroups; g += gridDim.x) {
        const int row0 = g * 64 + (threadIdx.x >> 6) * 16;
        int m = row0 + row; if (m >= N) m = N - 1;

        bf16x8 afr[4];
#pragma unroll
        for (int c = 0; c < 4; ++c) {
            const int k0 = c * 32 + kq * 8;
            afr[c] = *(const bf16x8*)(u + (size_t)m * 256 + k0);
        }

        f32x4 acc[8] = {};
#pragma unroll
        for (int t = 0; t < 8; ++t) {
            const int j  = t * 16 + row;
            const int jb = j & 7;
            const __bf16* base = wt + (j << 7);
#pragma unroll
            for (int c = 0; c < 4; ++c) {
                const int kb = c * 4 + kq;
                bf16x8 b = *(const bf16x8*)(base + ((kb ^ jb) << 3));
                acc[t] = MFMA16(afr[c], b, acc[t], 0, 0, 0);
            }
        }

#pragma unroll
        for (int t = 0; t < 8; ++t) {
            const int col = t * 16 + row;
            const float cc = c2[col];
#pragma unroll
            for (int q = 0; q < 4; ++q) {
                const int gr = row0 + kq * 4 + q;
                if (gr < N) out[(size_t)gr * 128 + col] = acc[t][q] + cc;
            }
        }
    }
}

extern "C" void kernel_launch(void* const* d_in, const int* in_sizes, int n_in,
                              void* d_out, int out_size, void* d_ws, size_t ws_size,
                              hipStream_t stream) {
    (void)n_in; (void)out_size;
    const float* x   = (const float*)d_in[0];
    const float* pos = (const float*)d_in[1];
    const int*   ei  = (const int*)d_in[2];
    const float* W1  = (const float*)d_in[3];
    const float* b1  = (const float*)d_in[4];
    const float* W2  = (const float*)d_in[5];
    const float* b2  = (const float*)d_in[6];
    const float* U1  = (const float*)d_in[7];
    const float* c1  = (const float*)d_in[8];
    const float* U2  = (const float*)d_in[9];
    const float* c2  = (const float*)d_in[10];

    const int N = in_sizes[0] / 128;
    const int E = in_sizes[2] / 2;

    // ---- workspace layout (16B-aligned slabs) ----
    const size_t aggr_b = (size_t)N * 128 * sizeof(float);
    const size_t Ni_b   = (((size_t)N * 4) + 15) & ~(size_t)15;
    const size_t E_b    = (((size_t)E * 4) + 15) & ~(size_t)15;
    size_t off = 0;
    char* base = (char*)d_ws;
    float* aggr   = (float*)(base + off); off += aggr_b;
    int*   flag   = (int*)  (base + off); off += 16;
    int*   counts = (int*)  (base + off); off += Ni_b;
    int*   offs   = (int*)  (base + off); off += Ni_b;
    int*   cursor = (int*)  (base + off); off += Ni_b;
    int*   parts  = (int*)  (base + off); off += 256 * 4;
    int*   csr_s  = (int*)  (base + off); off += E_b;
    int*   csr_r  = (int*)  (base + off); off += E_b;
    float* dist   = (float*)(base + off); off += E_b;
    const size_t need_csr = off;

    __bf16* u  = (__bf16*)d_ws;        // row stride 256 elem, aliases aggr
    __bf16* AB = (__bf16*)d_out;       // N*256 bf16 == out_nbytes

    const int nblk_scan = (N + 511) / 512;
    const bool csr_ok = (ws_size >= need_csr) && (nblk_scan <= 256);
    if (ws_size < aggr_b + 16 || !csr_ok) return;

    const int ng_nodes = (N + 63) / 64;
    const int grid_n   = ng_nodes < 512 ? ng_nodes : 512;
    const int grid_E   = (E + 255) / 256;
    const int grid_Nt  = (N + 255) / 256;
    const int nslot    = 2 * N;
    const int grid_f   = ((nslot + 3) / 4) < 2048 ? ((nslot + 3) / 4) : 2048;

    k_detect<<<1, 256, 0, stream>>>(ei, flag);
    k_node1<<<grid_n, 256, 0, stream>>>(x, W1, b1, AB, N, ng_nodes);

    hipMemsetAsync(counts, 0, (size_t)N * 4, stream);
    k_hist   <<<grid_E, 256, 0, stream>>>(ei, flag, counts, E);
    k_scan1  <<<nblk_scan, 256, 0, stream>>>(counts, offs, parts, N);
    k_scan2  <<<1, 256, 0, stream>>>(parts, nblk_scan);
    k_scan3  <<<grid_Nt, 256, 0, stream>>>(offs, parts, cursor, N);
    k_scatter<<<grid_E, 256, 0, stream>>>(ei, flag, pos, cursor,
                                          csr_s, csr_r, dist, E);

    k_edge_f4<<<grid_f, 256, 0, stream>>>(AB, csr_s, dist, offs, counts,
                                          W2, b2, W1 + 256 * 128, aggr, N);

    k_node2<<<grid_n, 256, 0, stream>>>(x, aggr, U1, c1, u, N, ng_nodes);
    k_node3<<<grid_n, 256, 0, stream>>>(u, U2, c2, (float*)d_out, N, ng_nodes);
}